// Round 12
// baseline (104.079 us; speedup 1.0000x reference)
//
#include <hip/hip_runtime.h>
#include <hip/hip_bf16.h>

#define B_ 8
#define T_ 16
#define D_ 1536
#define N_ 12
#define KH_ 2
#define G_ 6
#define H_ 128
#define S_ 8192
#define NCHUNK 48
#define SPLITS 8
#define SKV 4160           // padded key capacity (CUR+T <= 4160)
#define NTILE (SKV / 32)   // 130 packed tiles per (b,kh)
#define TILE_USH 8192      // per-tile ushorts: K frags 4096 + V frags 4096

typedef __attribute__((ext_vector_type(8))) short bf16x8;
typedef __attribute__((ext_vector_type(4))) float f32x4;
typedef __attribute__((ext_vector_type(4))) unsigned short u16x4;

__device__ __forceinline__ unsigned short f2bf(float x) {
    unsigned u = __float_as_uint(x);
    u += 0x7fffu + ((u >> 16) & 1u);
    return (unsigned short)(u >> 16);
}
__device__ __forceinline__ float bf2f(unsigned short h) {
    return __uint_as_float(((unsigned)h) << 16);
}

// ---------------------------------------------------------------------------
// Split-K MFMA GEMM with split-bf16 (3-product) accuracy. (unchanged)
// ---------------------------------------------------------------------------
__global__ __launch_bounds__(256, 4) void gemm_splitk(
    const float* __restrict__ A,
    const float* __restrict__ W0, int n0, int ldb0,
    const float* __restrict__ W1, int n1, int ldb1,
    const float* __restrict__ W2, int ldb2,
    float* __restrict__ part, int NTOT, int Kdim)
{
    __shared__ __align__(16) unsigned short Ah[64][40], Al[64][40];
    __shared__ __align__(16) unsigned short Bh[64][40], Bl[64][40];
    const int tid = threadIdx.x;
    const int wave = tid >> 6, lane = tid & 63;
    const int col = lane & 15, g = lane >> 4;
    const int row0 = blockIdx.y * 64;
    const int c0 = blockIdx.x * 64;
    const int ks = Kdim / gridDim.z;
    const int k0 = blockIdx.z * ks;

    const float* Bp; int ldb, bc0;
    if (c0 < n0)           { Bp = W0; ldb = ldb0; bc0 = c0; }
    else if (c0 < n0 + n1) { Bp = W1; ldb = ldb1; bc0 = c0 - n0; }
    else                   { Bp = W2; ldb = ldb2; bc0 = c0 - n0 - n1; }

    f32x4 acc[4];
#pragma unroll
    for (int nt = 0; nt < 4; ++nt) acc[nt] = (f32x4){0.f, 0.f, 0.f, 0.f};

    for (int kk = 0; kk < ks; kk += 32) {
        __syncthreads();
        if (tid < 128) {
#pragma unroll
            for (int c = tid; c < 512; c += 128) {
                int r = c >> 3, k4 = c & 7;
                float4 v = *(const float4*)&A[(size_t)(row0 + r) * Kdim + k0 + kk + k4 * 4];
                float f[4] = {v.x, v.y, v.z, v.w};
                u16x4 hv, lv;
#pragma unroll
                for (int i = 0; i < 4; ++i) {
                    unsigned short hh = f2bf(f[i]);
                    hv[i] = hh; lv[i] = f2bf(f[i] - bf2f(hh));
                }
                *(u16x4*)&Ah[r][k4 * 4] = hv;
                *(u16x4*)&Al[r][k4 * 4] = lv;
            }
        } else {
            int t2 = tid - 128;
            int kq = t2 >> 4, cq = t2 & 15;
            float a[4][4];
#pragma unroll
            for (int r = 0; r < 4; ++r) {
                float4 v = *(const float4*)&Bp[(size_t)(k0 + kk + kq * 4 + r) * ldb + bc0 + cq * 4];
                a[r][0] = v.x; a[r][1] = v.y; a[r][2] = v.z; a[r][3] = v.w;
            }
#pragma unroll
            for (int cc = 0; cc < 4; ++cc) {
                u16x4 hv, lv;
#pragma unroll
                for (int r = 0; r < 4; ++r) {
                    unsigned short hh = f2bf(a[r][cc]);
                    hv[r] = hh; lv[r] = f2bf(a[r][cc] - bf2f(hh));
                }
                *(u16x4*)&Bh[cq * 4 + cc][kq * 4] = hv;
                *(u16x4*)&Bl[cq * 4 + cc][kq * 4] = lv;
            }
        }
        __syncthreads();

        bf16x8 ah = *(const bf16x8*)&Ah[wave * 16 + col][g * 8];
        bf16x8 al = *(const bf16x8*)&Al[wave * 16 + col][g * 8];
#pragma unroll
        for (int nt = 0; nt < 4; ++nt) {
            bf16x8 bh = *(const bf16x8*)&Bh[nt * 16 + col][g * 8];
            bf16x8 bl = *(const bf16x8*)&Bl[nt * 16 + col][g * 8];
            acc[nt] = __builtin_amdgcn_mfma_f32_16x16x32_bf16(ah, bh, acc[nt], 0, 0, 0);
            acc[nt] = __builtin_amdgcn_mfma_f32_16x16x32_bf16(ah, bl, acc[nt], 0, 0, 0);
            acc[nt] = __builtin_amdgcn_mfma_f32_16x16x32_bf16(al, bh, acc[nt], 0, 0, 0);
        }
    }
#pragma unroll
    for (int nt = 0; nt < 4; ++nt)
#pragma unroll
        for (int j = 0; j < 4; ++j) {
            size_t prow = (size_t)blockIdx.z * 128 + row0 + wave * 16 + g * 4 + j;
            part[prow * NTOT + c0 + nt * 16 + col] = acc[nt][j];
        }
}

// ---------------------------------------------------------------------------
// Reduce SPLITS partials + bias + RoPE. (unchanged)
// ---------------------------------------------------------------------------
__global__ __launch_bounds__(256) void rope_reduce(
    const float* __restrict__ part,
    const float* __restrict__ bq, const float* __restrict__ bk,
    const float* __restrict__ bv,
    const int* __restrict__ seg, const int* __restrict__ curp,
    float* __restrict__ q_rope, float* __restrict__ k_new,
    float* __restrict__ v_new)
{
    const int row = blockIdx.x;
    const int b = row >> 4, t = row & 15;
    const int tid = threadIdx.x;
    __shared__ float S[2048];
    __shared__ float sc[64][2];

    const int CUR = curp[0];
    int c = 0;
    for (int tt = 0; tt <= t; ++tt) c += (seg[b * T_ + tt] != 0) ? 1 : 0;
    int pos = max(c - 1, 0) + CUR;

    if (tid < 64) {
        float frac = (2.0f * tid) / (float)H_;
        float ts = expf(frac * logf(1000000.0f));
        float ang = (float)pos / ts;
        sc[tid][0] = sinf(ang);
        sc[tid][1] = cosf(ang);
    }
    for (int e = tid; e < 2048; e += 256) {
        float s = 0.f;
#pragma unroll
        for (int sp = 0; sp < SPLITS; ++sp)
            s += part[((size_t)sp * 128 + row) * 2048 + e];
        S[e] = s;
    }
    __syncthreads();

    for (int e = tid; e < 768; e += 256) {
        int n = e >> 6, i = e & 63;
        float x1 = S[n * 128 + i] + bq[n * 128 + i];
        float x2 = S[n * 128 + i + 64] + bq[n * 128 + i + 64];
        float s = sc[i][0], co = sc[i][1];
        q_rope[(size_t)row * 1536 + n * 128 + i]      = x1 * co - x2 * s;
        q_rope[(size_t)row * 1536 + n * 128 + i + 64] = x2 * co + x1 * s;
    }
    if (tid < 128) {
        int n = tid >> 6, i = tid & 63;
        float x1 = S[1536 + n * 128 + i] + bk[n * 128 + i];
        float x2 = S[1536 + n * 128 + i + 64] + bk[n * 128 + i + 64];
        float s = sc[i][0], co = sc[i][1];
        k_new[(size_t)row * 256 + n * 128 + i]      = x1 * co - x2 * s;
        k_new[(size_t)row * 256 + n * 128 + i + 64] = x2 * co + x1 * s;
    }
    v_new[(size_t)row * 256 + tid] = S[1792 + tid] + bv[tid];
}

// ---------------------------------------------------------------------------
// Pack KV v2 (unchanged): bf16 MFMA fragments in lane order.
// ---------------------------------------------------------------------------
__global__ __launch_bounds__(256) void pack_kv(
    const float* __restrict__ k_cache, const float* __restrict__ v_cache,
    const float* __restrict__ k_new, const float* __restrict__ v_new,
    const int* __restrict__ curp,
    unsigned short* __restrict__ KVf)
{
    const int tile = blockIdx.x, b = blockIdx.y, kh = blockIdx.z;
    const int tid = threadIdx.x;
    const int CUR = curp[0], SPAN = CUR + T_;
    __shared__ float Ks[32][133], Vsh[32][133];
    const int s_base = tile * 32;
    const int rr = tid >> 5, d0 = (tid & 31) * 4;

#pragma unroll
    for (int i = 0; i < 4; ++i) {
        int r = rr + 8 * i;
        int s = min(s_base + r, SPAN - 1);
        const float* kr = (s < CUR)
            ? &k_cache[(((size_t)b * S_ + s) * KH_ + kh) * H_]
            : &k_new[(((size_t)b * T_ + (s - CUR)) * KH_ + kh) * H_];
        const float* vr = (s < CUR)
            ? &v_cache[(((size_t)b * S_ + s) * KH_ + kh) * H_]
            : &v_new[(((size_t)b * T_ + (s - CUR)) * KH_ + kh) * H_];
        *(float4*)&Ks[r][d0]  = *(const float4*)(kr + d0);
        *(float4*)&Vsh[r][d0] = *(const float4*)(vr + d0);
    }
    __syncthreads();

    unsigned short* KT = KVf + ((size_t)(b * KH_ + kh) * NTILE + tile) * TILE_USH;
    unsigned short* VT = KT + 4096;

#pragma unroll
    for (int hw = 0; hw < 2; ++hw) {
        const int w = tid + hw * 256;
        const int f = w >> 6, l = w & 63;
        const int col = l & 15, g = l >> 4;
        {
            const int key = (f >> 2) * 16 + col;
            const int dim = (f & 3) * 32 + g * 8;
            u16x4 o0, o1;
#pragma unroll
            for (int e = 0; e < 4; ++e) {
                o0[e] = f2bf(Ks[key][dim + e]);
                o1[e] = f2bf(Ks[key][dim + 4 + e]);
            }
            *(u16x4*)&KT[(size_t)w * 8]     = o0;
            *(u16x4*)&KT[(size_t)w * 8 + 4] = o1;
        }
        {
            const int dim = f * 16 + col;
            u16x4 o0, o1;
#pragma unroll
            for (int e = 0; e < 4; ++e) {
                o0[e] = f2bf(Vsh[g * 8 + e][dim]);
                o1[e] = f2bf(Vsh[g * 8 + 4 + e][dim]);
            }
            *(u16x4*)&VT[(size_t)w * 8]     = o0;
            *(u16x4*)&VT[(size_t)w * 8 + 4] = o1;
        }
    }
}

// ---------------------------------------------------------------------------
// MFMA flash attention v11: fragment-packed KV + coalesced aligned partials.
// grid = (NCHUNK=48, B, KH*2) = 1536 blocks (6/CU, 24 waves/CU), 256 thr.
// Partials: po[(chunk,b,kh,qi)][128] (512B-aligned rows, full-line writes);
// m/l in separate compact ml[...][2].
// ---------------------------------------------------------------------------
__global__ __launch_bounds__(256, 3) void attn_mfma(
    const float* __restrict__ q_rope,
    const unsigned short* __restrict__ KVf,
    const int* __restrict__ seg, const int* __restrict__ start_ind,
    const int* __restrict__ curp,
    float* __restrict__ po, float* __restrict__ ml)
{
    const int chunk = blockIdx.x, b = blockIdx.y;
    const int kh = blockIdx.z >> 1, half = blockIdx.z & 1;
    const int tid = threadIdx.x;
    const int wave = tid >> 6, lane = tid & 63;
    const int col = lane & 15, g = lane >> 4;
    const float scale = 0.088388347648318447f;
    const float NEG_INF = -__builtin_inff();

    const int CUR = curp[0];
    const int SPAN = CUR + T_;
    const int CH = (((SPAN + NCHUNK - 1) / NCHUNK) + 31) & ~31;  // multiple of 32
    const int s0 = chunk * CH;
    const int s1 = min(s0 + CH, SPAN);

    int st = start_ind[b];
    if (st < 0) {
        st = 0;
        for (int tt = 0; tt < T_; ++tt)
            if (seg[b * T_ + tt] != 0) { st = tt; break; }
    }

    __shared__ __align__(16) unsigned short Pl[4][16][40];

    const int qbase = half * 64 + wave * 16;
    const int qi_a = min(qbase + col, 95);
    const int t_a = (qi_a * 171) >> 10;
    const int gh_a = qi_a - t_a * G_;
    const float* qp = &q_rope[(((size_t)b * T_ + t_a) * N_ + kh * G_ + gh_a) * H_];
    bf16x8 qf[4];
#pragma unroll
    for (int ks = 0; ks < 4; ++ks) {
        float4 va = *(const float4*)&qp[ks * 32 + g * 8];
        float4 vb = *(const float4*)&qp[ks * 32 + g * 8 + 4];
        float f[8] = {va.x, va.y, va.z, va.w, vb.x, vb.y, vb.z, vb.w};
        union { bf16x8 v; __hip_bfloat162 h2[4]; } W;
#pragma unroll
        for (int i = 0; i < 4; ++i)
            W.h2[i] = __float22bfloat162_rn(make_float2(f[2 * i] * scale, f[2 * i + 1] * scale));
        qf[ks] = W.v;
    }

    int qpos_r[4], segid_r[4];
    bool wrow[4];
#pragma unroll
    for (int j = 0; j < 4; ++j) {
        int qi_raw = qbase + g * 4 + j;
        wrow[j] = (qi_raw < 96);
        int qi_c = min(qi_raw, 95);
        int t_c = (qi_c * 171) >> 10;
        segid_r[j] = seg[b * T_ + t_c];
        qpos_r[j] = CUR + t_c - st;
    }

    float m[4], lsum[4];
#pragma unroll
    for (int j = 0; j < 4; ++j) { m[j] = NEG_INF; lsum[j] = 0.f; }
    f32x4 oacc[8];
#pragma unroll
    for (int nt = 0; nt < 8; ++nt) oacc[nt] = (f32x4){0.f, 0.f, 0.f, 0.f};

    const unsigned short* KVbase = KVf + (size_t)(b * KH_ + kh) * NTILE * TILE_USH;

    auto loadK = [&](bf16x8* kf, int tileIdx) {
        const unsigned short* KT = KVbase + (size_t)tileIdx * TILE_USH;
#pragma unroll
        for (int f = 0; f < 8; ++f)
            kf[f] = *(const bf16x8*)&KT[(f * 64 + lane) * 8];
    };

    auto computeTile = [&](const bf16x8* kf, int tileIdx, int stile) {
        const unsigned short* VT = KVbase + (size_t)tileIdx * TILE_USH + 4096;
        bf16x8 vfr[8];
#pragma unroll
        for (int f = 0; f < 8; ++f)
            vfr[f] = *(const bf16x8*)&VT[(f * 64 + lane) * 8];

        f32x4 sacc0 = {0.f, 0.f, 0.f, 0.f}, sacc1 = {0.f, 0.f, 0.f, 0.f};
#pragma unroll
        for (int ks = 0; ks < 4; ++ks) {
            sacc0 = __builtin_amdgcn_mfma_f32_16x16x32_bf16(qf[ks], kf[ks], sacc0, 0, 0, 0);
            sacc1 = __builtin_amdgcn_mfma_f32_16x16x32_bf16(qf[ks], kf[4 + ks], sacc1, 0, 0, 0);
        }

        float rj[4];
        const int skey0 = stile + col, skey1 = stile + 16 + col;
#pragma unroll
        for (int j = 0; j < 4; ++j) {
            bool v0 = (skey0 < s1) && (skey0 - st <= qpos_r[j]) &&
                      (((skey0 >= st) ? 1 : 0) == segid_r[j]);
            bool v1 = (skey1 < s1) && (skey1 - st <= qpos_r[j]) &&
                      (((skey1 >= st) ? 1 : 0) == segid_r[j]);
            float lg0 = v0 ? sacc0[j] : NEG_INF;
            float lg1 = v1 ? sacc1[j] : NEG_INF;
            float tm = fmaxf(lg0, lg1);
            tm = fmaxf(tm, __shfl_xor(tm, 1));
            tm = fmaxf(tm, __shfl_xor(tm, 2));
            tm = fmaxf(tm, __shfl_xor(tm, 4));
            tm = fmaxf(tm, __shfl_xor(tm, 8));
            float mn = fmaxf(m[j], tm);
            float r, p0, p1;
            if (mn == NEG_INF) { r = 1.f; p0 = 0.f; p1 = 0.f; }
            else {
                r  = __expf(m[j] - mn);
                p0 = __expf(lg0 - mn);
                p1 = __expf(lg1 - mn);
            }
            float ps = p0 + p1;
            ps += __shfl_xor(ps, 1);
            ps += __shfl_xor(ps, 2);
            ps += __shfl_xor(ps, 4);
            ps += __shfl_xor(ps, 8);
            lsum[j] = lsum[j] * r + ps;
            m[j] = mn;
            rj[j] = r;
            int row = g * 4 + j;
            Pl[wave][row][col]      = f2bf(p0);
            Pl[wave][row][16 + col] = f2bf(p1);
        }

#pragma unroll
        for (int nt = 0; nt < 8; ++nt) {
#pragma unroll
            for (int j = 0; j < 4; ++j) oacc[nt][j] *= rj[j];
        }

        bf16x8 pa = *(const bf16x8*)&Pl[wave][col][g * 8];
#pragma unroll
        for (int nt = 0; nt < 8; ++nt)
            oacc[nt] = __builtin_amdgcn_mfma_f32_16x16x32_bf16(pa, vfr[nt], oacc[nt], 0, 0, 0);
    };

    const int nt_raw = (s1 - s0 + 31) >> 5;
    const int ntiles = (s1 > s0) ? nt_raw : 0;
    const int tile0 = s0 >> 5;
    bf16x8 kfA[8], kfB[8];
    if (ntiles > 0) loadK(kfA, tile0);
    for (int ti = 0; ti < ntiles; ti += 2) {
        if (ti + 1 < ntiles) loadK(kfB, tile0 + ti + 1);
        computeTile(kfA, tile0 + ti, s0 + ti * 32);
        if (ti + 1 < ntiles) {
            if (ti + 2 < ntiles) loadK(kfA, tile0 + ti + 2);
            computeTile(kfB, tile0 + ti + 1, s0 + (ti + 1) * 32);
        }
    }

    // ---- write partials: coalesced 512B-aligned O rows + compact m/l ----
    const size_t base_q = (((size_t)chunk * B_ + b) * KH_ + kh) * 96;
#pragma unroll
    for (int j = 0; j < 4; ++j) {
        if (!wrow[j]) continue;
        int qi = qbase + g * 4 + j;
        size_t row = base_q + qi;
        if (col == 0) { ml[row * 2] = m[j]; ml[row * 2 + 1] = lsum[j]; }
#pragma unroll
        for (int nt = 0; nt < 8; ++nt)
            po[row * 128 + nt * 16 + col] = oacc[nt][j];
    }
}

// ---------------------------------------------------------------------------
// Combine v3: one block per (qi, b, kh); aligned 512B row reads.
// ---------------------------------------------------------------------------
__global__ __launch_bounds__(128) void combine_kernel(
    const float* __restrict__ po, const float* __restrict__ ml,
    float* __restrict__ qkv)
{
    const int qi = blockIdx.x, b = blockIdx.y, kh = blockIdx.z;
    const int h = threadIdx.x;
    const size_t cstride = (size_t)B_ * KH_ * 96;   // rows per chunk
    const size_t row0 = ((size_t)b * KH_ + kh) * 96 + qi;

    __shared__ float sm[NCHUNK], sl[NCHUNK];
    if (h < NCHUNK) {
        sm[h] = ml[(row0 + (size_t)h * cstride) * 2];
        sl[h] = ml[(row0 + (size_t)h * cstride) * 2 + 1];
    }
    __syncthreads();

    float M = -__builtin_inff();
#pragma unroll
    for (int c = 0; c < NCHUNK; ++c) M = fmaxf(M, sm[c]);

    float den = 0.f, num = 0.f;
#pragma unroll
    for (int c = 0; c < NCHUNK; ++c) {
        float mc = sm[c];
        float e = (M == -__builtin_inff() || mc == -__builtin_inff())
                      ? 0.f : __expf(mc - M);
        den += e * sl[c];
        num += e * po[(row0 + (size_t)c * cstride) * 128 + h];
    }

    const int t = (qi * 171) >> 10;
    const int g = qi - t * G_;
    const int n = kh * G_ + g;
    qkv[(((size_t)b * T_ + t) * N_ + n) * H_ + h] = (den > 0.f) ? num / den : 0.f;
}

// ---------------------------------------------------------------------------
__global__ __launch_bounds__(256) void sum_reduce(
    const float* __restrict__ part, float* __restrict__ out, int n)
{
    int i = blockIdx.x * 256 + threadIdx.x;
    if (i < n) {
        float s = 0.f;
#pragma unroll
        for (int sp = 0; sp < SPLITS; ++sp) s += part[(size_t)sp * n + i];
        out[i] = s;
    }
}

// ---------------------------------------------------------------------------
extern "C" void kernel_launch(void* const* d_in, const int* in_sizes, int n_in,
                              void* d_out, int out_size, void* d_ws, size_t ws_size,
                              hipStream_t stream)
{
    (void)in_sizes; (void)n_in; (void)out_size; (void)ws_size;
    const float* x       = (const float*)d_in[0];
    const float* k_cache = (const float*)d_in[1];
    const float* v_cache = (const float*)d_in[2];
    const float* wq      = (const float*)d_in[3];
    const float* bq      = (const float*)d_in[4];
    const float* wk      = (const float*)d_in[5];
    const float* bk      = (const float*)d_in[6];
    const float* wv      = (const float*)d_in[7];
    const float* bv      = (const float*)d_in[8];
    const float* wo      = (const float*)d_in[9];
    const int*   seg     = (const int*)d_in[10];
    const int*   start_i = (const int*)d_in[11];
    const int*   curp    = (const int*)d_in[12];
    float* out = (float*)d_out;
    float* ws  = (float*)d_ws;

    // ws layout (floats unless noted). Projection partials (2.1M) and the
    // out-projection partials (1.57M) alias po (9.44M); lifetimes disjoint.
    const size_t POSZ = (size_t)NCHUNK * B_ * KH_ * 96 * 128; // 9,437,184
    const size_t MLSZ = (size_t)NCHUNK * B_ * KH_ * 96 * 2;  // 147,456
    const size_t QSZ  = (size_t)B_ * T_ * N_ * H_;           // 196,608
    const size_t KSZ  = (size_t)B_ * T_ * KH_ * H_;          // 32,768
    float* partP  = ws;
    float* po     = ws;
    float* ml     = ws + POSZ;
    float* q_rope = ml + MLSZ;
    float* k_new  = q_rope + QSZ;
    float* v_new  = k_new + KSZ;
    float* qkv    = v_new + KSZ;
    unsigned short* KVf = (unsigned short*)(qkv + QSZ);      // 17,039,360 ushorts

    gemm_splitk<<<dim3(32, 2, SPLITS), 256, 0, stream>>>(
        x, wq, 1536, 1536, wk, 256, 256, wv, 256, partP, 2048, D_);

    rope_reduce<<<B_ * T_, 256, 0, stream>>>(partP, bq, bk, bv, seg, curp,
                                             q_rope, k_new, v_new);

    pack_kv<<<dim3(NTILE, B_, KH_), 256, 0, stream>>>(
        k_cache, v_cache, k_new, v_new, curp, KVf);

    attn_mfma<<<dim3(NCHUNK, B_, KH_ * 2), 256, 0, stream>>>(
        q_rope, KVf, seg, start_i, curp, po, ml);

    combine_kernel<<<dim3(96, B_, KH_), 128, 0, stream>>>(po, ml, qkv);

    gemm_splitk<<<dim3(24, 2, SPLITS), 256, 0, stream>>>(
        qkv, wo, 1536, 1536, wo, 0, 1536, wo, 1536, partP, 1536, N_ * H_);

    sum_reduce<<<(B_ * T_ * D_ + 255) / 256, 256, 0, stream>>>(
        partP, out, B_ * T_ * D_);
}